// Round 5
// baseline (236.859 us; speedup 1.0000x reference)
//
#include <hip/hip_runtime.h>

// SoftClusterGaussianHead — moment formulation, occupancy-first round.
// B=8, N=4096, D=512, K=8.
// sigma = S2 + (S0-2)*S1^2 with S0=sum_n p, S1=sum_n p*x, S2=sum_n p*x^2.
// ws: P[B][N][K] | partial[b][chunk][k][d][2] | s0g[b][k]

typedef float v2f __attribute__((ext_vector_type(2)));

#define B_ 8
#define N_ 4096
#define D_ 512
#define K_ 8
#define EPS_ 1e-6f
#define CHUNKS 128           // blocks per b (both kA and kB)
#define P_FLOATS ((size_t)B_ * N_ * K_)
#define PART_FLOATS(cs) ((size_t)B_ * (cs) * K_ * D_ * 2)

// ---------------- kA: softmax probs + S0 ----------------
// 256 thr = 4 waves; wave does 8 rows (4 x 2-row ILP pairs); 32 rows/block.
__global__ __launch_bounds__(256, 3)
void kA_probs(const float* __restrict__ x, const float* __restrict__ W,
              const float* __restrict__ bias, float* __restrict__ P,
              float* __restrict__ s0g) {
#pragma clang fp contract(fast)
  const int lane = threadIdx.x & 63;
  const int wave = threadIdx.x >> 6;
  const int b    = blockIdx.x >> 7;
  const int chunk= blockIdx.x & 127;
  const int m    = lane & 7;
  const int grp  = lane >> 3;
  const int d0   = lane * 4;

  // Preload W fragments: wk[dj][kp] = (W[d][2kp], W[d][2kp+1])
  v2f wk[8][4];
#pragma unroll
  for (int c = 0; c < 4; ++c) {
    const float4* wr0 = reinterpret_cast<const float4*>(&W[(d0 + c) * K_]);
    float4 wa = wr0[0], wb = wr0[1];
    wk[c][0] = (v2f){wa.x, wa.y}; wk[c][1] = (v2f){wa.z, wa.w};
    wk[c][2] = (v2f){wb.x, wb.y}; wk[c][3] = (v2f){wb.z, wb.w};
    const float4* wr1 = reinterpret_cast<const float4*>(&W[(256 + d0 + c) * K_]);
    float4 wc = wr1[0], wd = wr1[1];
    wk[4+c][0] = (v2f){wc.x, wc.y}; wk[4+c][1] = (v2f){wc.z, wc.w};
    wk[4+c][2] = (v2f){wd.x, wd.y}; wk[4+c][3] = (v2f){wd.z, wd.w};
  }
  const float biasv = bias[m];

  const bool s_c0 = (lane & 1) != 0;
  const bool s_c1 = (lane & 2) != 0;
  const bool s_c2 = (lane & 4) != 0;

  const int wrow = chunk * 32 + wave * 8;
  const float* xb = x + (size_t)b * N_ * D_;

  auto row_softmax = [&](float4 xa, float4 xc) -> float {
    float xv[8] = {xa.x, xa.y, xa.z, xa.w, xc.x, xc.y, xc.z, xc.w};
    v2f qp[4] = {(v2f){0,0},(v2f){0,0},(v2f){0,0},(v2f){0,0}};
#pragma unroll
    for (int dj = 0; dj < 8; ++dj) {
      v2f xx = (v2f){xv[dj], xv[dj]};
#pragma unroll
      for (int kp = 0; kp < 4; ++kp) qp[kp] += wk[dj][kp] * xx;
    }
    float q0=qp[0].x,q1=qp[0].y,q2=qp[1].x,q3=qp[1].y;
    float q4=qp[2].x,q5=qp[2].y,q6=qp[3].x,q7=qp[3].y;
    // reduce-scatter butterfly: lane ends with full logit for k = lane&7
    float r0 = s_c0 ? q0 : q1, r1 = s_c0 ? q2 : q3, r2 = s_c0 ? q4 : q5, r3 = s_c0 ? q6 : q7;
    r0 = __shfl_xor(r0, 1, 64); r1 = __shfl_xor(r1, 1, 64);
    r2 = __shfl_xor(r2, 1, 64); r3 = __shfl_xor(r3, 1, 64);
    float a0 = (s_c0 ? q1 : q0) + r0, a1 = (s_c0 ? q3 : q2) + r1;
    float a2 = (s_c0 ? q5 : q4) + r2, a3 = (s_c0 ? q7 : q6) + r3;
    float s0g_ = s_c1 ? a0 : a1, s1g_ = s_c1 ? a2 : a3;
    s0g_ = __shfl_xor(s0g_, 2, 64); s1g_ = __shfl_xor(s1g_, 2, 64);
    float b0 = (s_c1 ? a1 : a0) + s0g_, b1 = (s_c1 ? a3 : a2) + s1g_;
    float g0 = s_c2 ? b0 : b1;
    g0 = __shfl_xor(g0, 4, 64);
    float t = (s_c2 ? b1 : b0) + g0;
    t += __shfl_xor(t, 8, 64);
    t += __shfl_xor(t, 16, 64);
    t += __shfl_xor(t, 32, 64);
    t += biasv;
    // softmax in transposed (one-k-per-lane) form
    float mx = fmaxf(t, __shfl_xor(t, 1, 64));
    mx = fmaxf(mx, __shfl_xor(mx, 2, 64));
    mx = fmaxf(mx, __shfl_xor(mx, 4, 64));
    float e = __expf(t - mx);
    float se = e + __shfl_xor(e, 1, 64);
    se += __shfl_xor(se, 2, 64);
    se += __shfl_xor(se, 4, 64);
    return e * __builtin_amdgcn_rcpf(se);
  };

  float s0acc = 0.f;
  float psel = 0.f;
#pragma unroll
  for (int pair = 0; pair < 4; ++pair) {
    const int r0 = wrow + pair * 2;
    const float4* x0 = reinterpret_cast<const float4*>(&xb[(size_t)r0 * D_]);
    const float4* x1 = reinterpret_cast<const float4*>(&xb[(size_t)(r0 + 1) * D_]);
    float4 xa0 = x0[lane], xc0 = x0[64 + lane];
    float4 xa1 = x1[lane], xc1 = x1[64 + lane];
    float pm0 = row_softmax(xa0, xc0);
    float pm1 = row_softmax(xa1, xc1);
    s0acc += pm0 + pm1;
    psel = (grp == pair * 2)     ? pm0 : psel;
    psel = (grp == pair * 2 + 1) ? pm1 : psel;
  }
  // coalesced P store: lane = j*8+k covers the wave's 8 rows
  P[((size_t)b * N_ + wrow) * K_ + lane] = psel;

  // block S0 -> 8 device atomics
  __shared__ float s0sh[4][K_];
  if (lane < K_) s0sh[wave][lane] = s0acc;
  __syncthreads();
  if (threadIdx.x < K_) {
    float s = s0sh[0][threadIdx.x] + s0sh[1][threadIdx.x] +
              s0sh[2][threadIdx.x] + s0sh[3][threadIdx.x];
    atomicAdd(s0g + b * K_ + threadIdx.x, s);
  }
}

// ---------------- kB: weighted moments ----------------
// 256 thr = 4 waves = 2 rowgroups x 2 k-halves; 16 rows/wave; 32 rows/block.
__global__ __launch_bounds__(256, 4)
void kB_moments(const float* __restrict__ x, const float* __restrict__ P,
                float* __restrict__ partial, int cstride, int atomic_mode) {
#pragma clang fp contract(fast)
  const int lane  = threadIdx.x & 63;
  const int wave  = threadIdx.x >> 6;
  const int khalf = wave & 1;
  const int rowg  = wave >> 1;
  const int b     = blockIdx.x >> 7;
  const int chunk = blockIdx.x & 127;

  v2f acc[8][4];
#pragma unroll
  for (int dj = 0; dj < 8; ++dj)
#pragma unroll
    for (int kk = 0; kk < 4; ++kk) acc[dj][kk] = (v2f){0.f, 0.f};

  const int row_base = chunk * 32 + rowg * 16;
  const float* xb = x + (size_t)b * N_ * D_;
  const float* Pr = P + ((size_t)b * N_ + row_base) * K_ + khalf * 4;

  const float4* xr = reinterpret_cast<const float4*>(&xb[(size_t)row_base * D_]);
  float4 xa = xr[lane];
  float4 xc = xr[64 + lane];
  float4 pv = *reinterpret_cast<const float4*>(Pr);

  for (int i = 0; i < 16; ++i) {
    const int ni = (i + 1 < 16) ? i + 1 : i;
    const float4* xrn = reinterpret_cast<const float4*>(&xb[(size_t)(row_base + ni) * D_]);
    float4 na = xrn[lane];
    float4 nc = xrn[64 + lane];
    float4 npv = *reinterpret_cast<const float4*>(Pr + (size_t)ni * K_);

    float xv[8] = {xa.x, xa.y, xa.z, xa.w, xc.x, xc.y, xc.z, xc.w};
    float pk[4] = {pv.x, pv.y, pv.z, pv.w};

#pragma unroll
    for (int dj = 0; dj < 8; ++dj) {
      v2f m2 = (v2f){xv[dj], xv[dj] * xv[dj]};
#pragma unroll
      for (int kk = 0; kk < 4; ++kk) {
        v2f pp = (v2f){pk[kk], pk[kk]};
        acc[dj][kk] += m2 * pp;
      }
    }
    xa = na; xc = nc; pv = npv;
  }

  // ---- LDS combine across 4 waves (merge rowgroups, keep k-halves) ----
  const int cslot = atomic_mode ? 0 : chunk;
  __shared__ v2f sh[4][2][4][64];   // 16 KB

#pragma unroll
  for (int r = 0; r < 4; ++r) {
#pragma unroll
    for (int kk = 0; kk < 4; ++kk) {
      sh[wave][0][kk][lane] = acc[2 * r][kk];
      sh[wave][1][kk][lane] = acc[2 * r + 1][kk];
    }
    __syncthreads();
    const int k8 = threadIdx.x >> 5;       // 0..7 global k
    const int w0 = k8 >> 2;                // khalf -> waves w0, w0+2
    const int kk = k8 & 3;
#pragma unroll
    for (int half = 0; half < 2; ++half) {
      const int slot = (threadIdx.x & 31) + 32 * half;
      v2f sA = sh[w0][0][kk][slot] + sh[w0 + 2][0][kk][slot];
      v2f sB = sh[w0][1][kk][slot] + sh[w0 + 2][1][kk][slot];
      const int dbase = (r < 2) ? (slot * 4 + 2 * r) : (256 + slot * 4 + 2 * (r - 2));
      float* dst = partial + (((size_t)(b * cstride + cslot) * K_ + k8) * D_ + dbase) * 2;
      if (atomic_mode) {
        atomicAdd(dst + 0, sA.x); atomicAdd(dst + 1, sA.y);
        atomicAdd(dst + 2, sB.x); atomicAdd(dst + 3, sB.y);
      } else {
        float4 v; v.x = sA.x; v.y = sA.y; v.z = sB.x; v.w = sB.y;
        *reinterpret_cast<float4*>(dst) = v;
      }
    }
    __syncthreads();
  }
}

// ---------------- k2: finalize ----------------
// grid = B*32 slices, 256 thr: cq(2) x k(8) x dl(16); cq splits the chunk sum.
__global__ __launch_bounds__(256)
void k2_final(const float* __restrict__ partial, const float* __restrict__ s0g,
              const float* __restrict__ eps, float* __restrict__ out,
              int cstride, int nchunks) {
  const int b = blockIdx.x >> 5;
  const int slice = blockIdx.x & 31;
  const int tid = threadIdx.x;
  const int cq = tid >> 7;
  const int k  = (tid >> 4) & 7;
  const int dl = tid & 15;
  const int d  = slice * 16 + dl;

  __shared__ v2f red2[2][K_][16];
  __shared__ float zsh[K_][16];
  __shared__ float klsh[4];

  const int half = (nchunks + 1) >> 1;
  const int cbeg = cq * half;
  const int cend = (cbeg + half < nchunks) ? (cbeg + half) : nchunks;

  const float* base = partial + (((size_t)b * cstride) * K_ + k) * D_ * 2 + d * 2;
  const size_t cstep = (size_t)K_ * D_ * 2;

  v2f s0v = (v2f){0,0}, s1v = (v2f){0,0}, s2v = (v2f){0,0}, s3v = (v2f){0,0};
  int c = cbeg;
  for (; c + 4 <= cend; c += 4) {
    s0v += *reinterpret_cast<const v2f*>(base + (size_t)c * cstep);
    s1v += *reinterpret_cast<const v2f*>(base + (size_t)(c + 1) * cstep);
    s2v += *reinterpret_cast<const v2f*>(base + (size_t)(c + 2) * cstep);
    s3v += *reinterpret_cast<const v2f*>(base + (size_t)(c + 3) * cstep);
  }
  for (; c < cend; ++c) s0v += *reinterpret_cast<const v2f*>(base + (size_t)c * cstep);
  red2[cq][k][dl] = (s0v + s1v) + (s2v + s3v);
  __syncthreads();

  float klp = 0.f;
  if (cq == 0) {
    v2f sv = red2[0][k][dl] + red2[1][k][dl];
    const float S1 = sv.x, S2 = sv.y;
    const float S0 = s0g[b * K_ + k];
    float sigraw = S2 + (S0 - 2.f) * S1 * S1;
    float sig = fmaxf(sigraw, 0.f) + EPS_;
    float z = S1 + eps[((size_t)(b * K_ + k)) * D_ + d] * sqrtf(sig);
    zsh[k][dl] = z;
    klp = 1.f + logf(sig) - S1 * S1 - sigraw;
  }

  klp += __shfl_xor(klp, 1, 64);
  klp += __shfl_xor(klp, 2, 64);
  klp += __shfl_xor(klp, 4, 64);
  klp += __shfl_xor(klp, 8, 64);
  klp += __shfl_xor(klp, 16, 64);
  klp += __shfl_xor(klp, 32, 64);
  const int lane = tid & 63, wv = tid >> 6;
  if (lane == 0) klsh[wv] = klp;
  __syncthreads();

  if (tid < 16) {
    float pooled = 0.f;
#pragma unroll
    for (int kk = 0; kk < K_; ++kk) pooled += zsh[kk][tid];
    out[b * D_ + slice * 16 + tid] = pooled * 0.125f;
  }
  if (tid == 0) {
    atomicAdd(out + B_ * D_, (klsh[0] + klsh[1] + klsh[2] + klsh[3]) * (-0.5f / (B_ * K_)));
  }
}

extern "C" void kernel_launch(void* const* d_in, const int* in_sizes, int n_in,
                              void* d_out, int out_size, void* d_ws, size_t ws_size,
                              hipStream_t stream) {
  const float* x    = (const float*)d_in[0];
  const float* W    = (const float*)d_in[1];
  const float* bias = (const float*)d_in[2];
  const float* eps  = (const float*)d_in[3];
  float* out = (float*)d_out;
  float* ws  = (float*)d_ws;

  const size_t full_floats = P_FLOATS + PART_FLOATS(CHUNKS) + B_ * K_;
  const int atomic_mode = (ws_size < full_floats * sizeof(float)) ? 1 : 0;
  const int cstride = atomic_mode ? 1 : CHUNKS;
  const int nchunks = atomic_mode ? 1 : CHUNKS;

  float* P       = ws;
  float* partial = ws + P_FLOATS;
  float* s0g     = partial + PART_FLOATS(cstride);

  if (atomic_mode) {
    hipMemsetAsync(partial, 0, (PART_FLOATS(1) + B_ * K_) * sizeof(float), stream);
  } else {
    hipMemsetAsync(s0g, 0, B_ * K_ * sizeof(float), stream);
  }
  hipMemsetAsync(out + B_ * D_, 0, sizeof(float), stream);

  kA_probs  <<<B_ * CHUNKS, 256, 0, stream>>>(x, W, bias, P, s0g);
  kB_moments<<<B_ * CHUNKS, 256, 0, stream>>>(x, P, partial, cstride, atomic_mode);
  k2_final  <<<B_ * 32, 256, 0, stream>>>(partial, s0g, eps, out, cstride, nchunks);
}

// Round 6
// 52.086 us; speedup vs baseline: 4.5474x; 4.5474x over previous
//
#include <hip/hip_runtime.h>

// SoftClusterGaussianHead — fused two-phase kernel with temporal register reuse.
// B=8, N=4096, D=512, K=8.
// sigma = S2 + (S0-2)*S1^2 with S0=sum_n p, S1=sum_n p*x, S2=sum_n p*x^2.
// Phase 1 (live: wk ~115 regs): softmax p -> LDS. Phase 2 (live: acc ~80 regs):
// moment accumulation, x re-read is L1/L2-hot. Never both live at once.
// ws: partial[b][chunk][k][d][2] | s0g[b][k]

typedef float v2f __attribute__((ext_vector_type(2)));

#define B_ 8
#define N_ 4096
#define D_ 512
#define K_ 8
#define EPS_ 1e-6f
#define CHUNKS 64            // blocks per b
#define ROWS_PB 64           // rows per block
#define PART_FLOATS(cs) ((size_t)B_ * (cs) * K_ * D_ * 2)

__global__ __launch_bounds__(512, 2)
void k1_fused(const float* __restrict__ x, const float* __restrict__ W,
              const float* __restrict__ bias, float* __restrict__ partial,
              float* __restrict__ s0g, int cstride, int atomic_mode) {
#pragma clang fp contract(fast)
  const int lane = threadIdx.x & 63;
  const int wave = threadIdx.x >> 6;
  const int b     = blockIdx.x >> 6;
  const int chunk = blockIdx.x & 63;

  __shared__ float p_lds[ROWS_PB][K_];   // 2 KB
  __shared__ v2f   comb[4][16][64];      // 32 KB
  __shared__ float s0sh[8][K_];          // 256 B

  const float* xb = x + ((size_t)b * N_ + (size_t)chunk * ROWS_PB) * D_;

  // ---------------- phase 1: softmax probs (lane owns d = 8*lane..8*lane+7) ----
  {
    v2f wk[8][4];
#pragma unroll
    for (int dj = 0; dj < 8; ++dj) {
      const float4* wr = reinterpret_cast<const float4*>(&W[(8 * lane + dj) * K_]);
      float4 wa = wr[0], wb4 = wr[1];
      wk[dj][0] = (v2f){wa.x, wa.y};  wk[dj][1] = (v2f){wa.z, wa.w};
      wk[dj][2] = (v2f){wb4.x, wb4.y}; wk[dj][3] = (v2f){wb4.z, wb4.w};
    }
    const float biasv = bias[lane & 7];
    const bool c0 = (lane & 1) != 0;
    const bool c1 = (lane & 2) != 0;
    const bool c2 = (lane & 4) != 0;

    float s0acc = 0.f;
    for (int j = 0; j < 8; ++j) {
      const int row = wave * 8 + j;
      const float4* xr = reinterpret_cast<const float4*>(&xb[(size_t)row * D_]);
      float4 xa = xr[2 * lane];
      float4 xc = xr[2 * lane + 1];
      float xv[8] = {xa.x, xa.y, xa.z, xa.w, xc.x, xc.y, xc.z, xc.w};

      v2f qp[4] = {(v2f){0,0},(v2f){0,0},(v2f){0,0},(v2f){0,0}};
#pragma unroll
      for (int dj = 0; dj < 8; ++dj) {
        v2f xx = (v2f){xv[dj], xv[dj]};
#pragma unroll
        for (int kp = 0; kp < 4; ++kp) qp[kp] += wk[dj][kp] * xx;
      }
      float q0=qp[0].x,q1=qp[0].y,q2=qp[1].x,q3=qp[1].y;
      float q4=qp[2].x,q5=qp[2].y,q6=qp[3].x,q7=qp[3].y;

      // reduce-scatter butterfly: lane ends with full logit for k = lane&7
      float r0 = c0 ? q0 : q1, r1 = c0 ? q2 : q3, r2 = c0 ? q4 : q5, r3 = c0 ? q6 : q7;
      r0 = __shfl_xor(r0, 1, 64); r1 = __shfl_xor(r1, 1, 64);
      r2 = __shfl_xor(r2, 1, 64); r3 = __shfl_xor(r3, 1, 64);
      float a0 = (c0 ? q1 : q0) + r0, a1 = (c0 ? q3 : q2) + r1;
      float a2 = (c0 ? q5 : q4) + r2, a3 = (c0 ? q7 : q6) + r3;
      float sg0 = c1 ? a0 : a1, sg1 = c1 ? a2 : a3;
      sg0 = __shfl_xor(sg0, 2, 64); sg1 = __shfl_xor(sg1, 2, 64);
      float b0 = (c1 ? a1 : a0) + sg0, b1 = (c1 ? a3 : a2) + sg1;
      float g0 = c2 ? b0 : b1;
      g0 = __shfl_xor(g0, 4, 64);
      float t = (c2 ? b1 : b0) + g0;
      t += __shfl_xor(t, 8, 64);
      t += __shfl_xor(t, 16, 64);
      t += __shfl_xor(t, 32, 64);
      t += biasv;

      // softmax in transposed (one-k-per-lane) form
      float mx = fmaxf(t, __shfl_xor(t, 1, 64));
      mx = fmaxf(mx, __shfl_xor(mx, 2, 64));
      mx = fmaxf(mx, __shfl_xor(mx, 4, 64));
      float e = __expf(t - mx);
      float se = e + __shfl_xor(e, 1, 64);
      se += __shfl_xor(se, 2, 64);
      se += __shfl_xor(se, 4, 64);
      float pm = e * __builtin_amdgcn_rcpf(se);

      s0acc += pm;
      if (lane < K_) p_lds[row][lane] = pm;
    }
    if (lane < K_) s0sh[wave][lane] = s0acc;
  }
  __syncthreads();

  if (threadIdx.x < K_) {
    float s = 0.f;
#pragma unroll
    for (int w = 0; w < 8; ++w) s += s0sh[w][threadIdx.x];
    atomicAdd(s0g + b * K_ + threadIdx.x, s);
  }

  // ---------------- phase 2: moments. wave = (k-pair q, row-half h) -----------
  const int q = wave & 3;
  const int h = wave >> 2;
  const int rbase = h * 32;

  v2f acc[8][2];
#pragma unroll
  for (int dj = 0; dj < 8; ++dj) { acc[dj][0] = (v2f){0,0}; acc[dj][1] = (v2f){0,0}; }

  // software-pipelined: prefetch next row's x and p
  const float4* xr0 = reinterpret_cast<const float4*>(&xb[(size_t)rbase * D_]);
  float4 xa = xr0[2 * lane];
  float4 xc = xr0[2 * lane + 1];
  v2f pk = *reinterpret_cast<const v2f*>(&p_lds[rbase][2 * q]);

  for (int r = 0; r < 32; ++r) {
    const int nr = rbase + ((r + 1 < 32) ? r + 1 : r);
    const float4* xrn = reinterpret_cast<const float4*>(&xb[(size_t)nr * D_]);
    float4 na = xrn[2 * lane];
    float4 nc = xrn[2 * lane + 1];
    v2f npk = *reinterpret_cast<const v2f*>(&p_lds[nr][2 * q]);

    float xv[8] = {xa.x, xa.y, xa.z, xa.w, xc.x, xc.y, xc.z, xc.w};
    v2f p0 = (v2f){pk.x, pk.x};
    v2f p1 = (v2f){pk.y, pk.y};
#pragma unroll
    for (int dj = 0; dj < 8; ++dj) {
      v2f m2 = (v2f){xv[dj], xv[dj] * xv[dj]};
      acc[dj][0] += m2 * p0;
      acc[dj][1] += m2 * p1;
    }
    xa = na; xc = nc; pk = npk;
  }

  // row-half merge via LDS, then coalesced flush by h==0 waves
  if (h == 1) {
#pragma unroll
    for (int dj = 0; dj < 8; ++dj) {
      comb[q][dj * 2 + 0][lane] = acc[dj][0];
      comb[q][dj * 2 + 1][lane] = acc[dj][1];
    }
  }
  __syncthreads();

  if (h == 0) {
    const int cslot = atomic_mode ? 0 : chunk;
#pragma unroll
    for (int kk = 0; kk < 2; ++kk) {
      const int k = 2 * q + kk;
      float* dst = partial + (((size_t)(b * cstride + cslot) * K_ + k) * D_ + 8 * lane) * 2;
#pragma unroll
      for (int g = 0; g < 4; ++g) {
        v2f u0 = acc[2 * g][kk]     + comb[q][(2 * g) * 2 + kk][lane];
        v2f u1 = acc[2 * g + 1][kk] + comb[q][(2 * g + 1) * 2 + kk][lane];
        if (atomic_mode) {
          atomicAdd(dst + g * 4 + 0, u0.x); atomicAdd(dst + g * 4 + 1, u0.y);
          atomicAdd(dst + g * 4 + 2, u1.x); atomicAdd(dst + g * 4 + 3, u1.y);
        } else {
          float4 v; v.x = u0.x; v.y = u0.y; v.z = u1.x; v.w = u1.y;
          *reinterpret_cast<float4*>(dst + g * 4) = v;   // 64B-aligned, coalesced
        }
      }
    }
  }
}

// ---------------- k2: finalize ----------------
// grid = B*32 slices, 256 thr: cq(2) x k(8) x dl(16); cq splits the chunk sum.
__global__ __launch_bounds__(256)
void k2_final(const float* __restrict__ partial, const float* __restrict__ s0g,
              const float* __restrict__ eps, float* __restrict__ out,
              int cstride, int nchunks) {
  const int b = blockIdx.x >> 5;
  const int slice = blockIdx.x & 31;
  const int tid = threadIdx.x;
  const int cq = tid >> 7;
  const int k  = (tid >> 4) & 7;
  const int dl = tid & 15;
  const int d  = slice * 16 + dl;

  __shared__ v2f red2[2][K_][16];
  __shared__ float zsh[K_][16];
  __shared__ float klsh[4];

  const int half = (nchunks + 1) >> 1;
  const int cbeg = cq * half;
  const int cend = (cbeg + half < nchunks) ? (cbeg + half) : nchunks;

  const float* base = partial + (((size_t)b * cstride) * K_ + k) * D_ * 2 + d * 2;
  const size_t cstep = (size_t)K_ * D_ * 2;

  v2f s0v = (v2f){0,0}, s1v = (v2f){0,0}, s2v = (v2f){0,0}, s3v = (v2f){0,0};
  int c = cbeg;
  for (; c + 4 <= cend; c += 4) {
    s0v += *reinterpret_cast<const v2f*>(base + (size_t)c * cstep);
    s1v += *reinterpret_cast<const v2f*>(base + (size_t)(c + 1) * cstep);
    s2v += *reinterpret_cast<const v2f*>(base + (size_t)(c + 2) * cstep);
    s3v += *reinterpret_cast<const v2f*>(base + (size_t)(c + 3) * cstep);
  }
  for (; c < cend; ++c) s0v += *reinterpret_cast<const v2f*>(base + (size_t)c * cstep);
  red2[cq][k][dl] = (s0v + s1v) + (s2v + s3v);
  __syncthreads();

  float klp = 0.f;
  if (cq == 0) {
    v2f sv = red2[0][k][dl] + red2[1][k][dl];
    const float S1 = sv.x, S2 = sv.y;
    const float S0 = s0g[b * K_ + k];
    float sigraw = S2 + (S0 - 2.f) * S1 * S1;
    float sig = fmaxf(sigraw, 0.f) + EPS_;
    float z = S1 + eps[((size_t)(b * K_ + k)) * D_ + d] * sqrtf(sig);
    zsh[k][dl] = z;
    klp = 1.f + logf(sig) - S1 * S1 - sigraw;
  }

  klp += __shfl_xor(klp, 1, 64);
  klp += __shfl_xor(klp, 2, 64);
  klp += __shfl_xor(klp, 4, 64);
  klp += __shfl_xor(klp, 8, 64);
  klp += __shfl_xor(klp, 16, 64);
  klp += __shfl_xor(klp, 32, 64);
  const int lane = tid & 63, wv = tid >> 6;
  if (lane == 0) klsh[wv] = klp;
  __syncthreads();

  if (tid < 16) {
    float pooled = 0.f;
#pragma unroll
    for (int kk = 0; kk < K_; ++kk) pooled += zsh[kk][tid];
    out[b * D_ + slice * 16 + tid] = pooled * 0.125f;
  }
  if (tid == 0) {
    atomicAdd(out + B_ * D_, (klsh[0] + klsh[1] + klsh[2] + klsh[3]) * (-0.5f / (B_ * K_)));
  }
}

extern "C" void kernel_launch(void* const* d_in, const int* in_sizes, int n_in,
                              void* d_out, int out_size, void* d_ws, size_t ws_size,
                              hipStream_t stream) {
  const float* x    = (const float*)d_in[0];
  const float* W    = (const float*)d_in[1];
  const float* bias = (const float*)d_in[2];
  const float* eps  = (const float*)d_in[3];
  float* out = (float*)d_out;
  float* ws  = (float*)d_ws;

  const size_t full_floats = PART_FLOATS(CHUNKS) + B_ * K_;
  const int atomic_mode = (ws_size < full_floats * sizeof(float)) ? 1 : 0;
  const int cstride = atomic_mode ? 1 : CHUNKS;
  const int nchunks = atomic_mode ? 1 : CHUNKS;

  float* partial = ws;
  float* s0g     = partial + PART_FLOATS(cstride);

  if (atomic_mode) {
    hipMemsetAsync(partial, 0, (PART_FLOATS(1) + B_ * K_) * sizeof(float), stream);
  } else {
    hipMemsetAsync(s0g, 0, B_ * K_ * sizeof(float), stream);
  }
  hipMemsetAsync(out + B_ * D_, 0, sizeof(float), stream);

  k1_fused<<<B_ * CHUNKS, 512, 0, stream>>>(x, W, bias, partial, s0g, cstride, atomic_mode);
  k2_final<<<B_ * 32, 256, 0, stream>>>(partial, s0g, eps, out, cstride, nchunks);
}